// Round 9
// baseline (990.247 us; speedup 1.0000x reference)
//
#include <hip/hip_runtime.h>

static constexpr int ND1=160, ND2=160, ND3=32;
static constexpr int SP  = ND1*ND2*ND3;        // 819200
static constexpr int CO  = 64;
static constexpr int OD1=80, OD2=80, OD3=32;
static constexpr int OSP = OD1*OD2*OD3;        // 204800
static constexpr int NSC = 64;                 // stat copies (contention spread)

typedef __attribute__((ext_vector_type(8))) short  short8;
typedef __attribute__((ext_vector_type(4))) float  f32x4;

__device__ __forceinline__ float b2f(unsigned u){ return __uint_as_float(u<<16); }
__device__ __forceinline__ unsigned short f2b(float f){
    unsigned u = __float_as_uint(f);
    u += 0x7fffu + ((u>>16)&1u);
    return (unsigned short)(u>>16);
}

// ---------------- mask dtype detection ----------------
__global__ void k_detect(const unsigned char* __restrict__ mb, int* __restrict__ flag)
{
    __shared__ int lf;
    if (threadIdx.x == 0) lf = 0;
    __syncthreads();
    int f = 0;
    for (int i = blockIdx.x*256 + threadIdx.x; i < SP; i += gridDim.x*256) {
        unsigned char b = mb[i];
        if (b > 1) f |= 4;
        if (b != 0 && (i & 3)) f |= 1;
    }
    if (f) atomicOr(&lf, f);
    __syncthreads();
    if (threadIdx.x == 0 && lf) atomicOr(flag, lf);
}

__global__ void k_mask(const void* __restrict__ mraw, const int* __restrict__ flag,
                       float* __restrict__ m, float* __restrict__ nactN)
{
    int i = blockIdx.x*256 + threadIdx.x;
    int f = *flag;
    float v;
    if (f & 4)      v = (reinterpret_cast<const float*>(mraw)[i] != 0.f) ? 1.f : 0.f;
    else if (f & 1) v = (reinterpret_cast<const unsigned char*>(mraw)[i] != 0) ? 1.f : 0.f;
    else            v = (reinterpret_cast<const int*>(mraw)[i] != 0) ? 1.f : 0.f;
    m[i] = v;
    float s = v;
    #pragma unroll
    for (int off = 32; off > 0; off >>= 1) s += __shfl_xor(s, off);
    __shared__ float wsum[4];
    if ((threadIdx.x & 63) == 0) wsum[threadIdx.x >> 6] = s;
    __syncthreads();
    if (threadIdx.x == 0) atomicAdd(&nactN[blockIdx.x & (NSC-1)], wsum[0]+wsum[1]+wsum[2]+wsum[3]);
}

__global__ void k_outmask(const float* __restrict__ m, float* __restrict__ om)
{
    int i = blockIdx.x*256 + threadIdx.x;   // < OSP
    int o3 = i & 31; int t = i >> 5; int o2 = t % OD2; int o1 = t / OD2;
    float s = 0.f;
    for (int kd = 0; kd < 3; kd++) { int d1 = 2*o1 - 1 + kd; if ((unsigned)d1 >= ND1) continue;
      for (int kh = 0; kh < 3; kh++) { int d2 = 2*o2 - 1 + kh; if ((unsigned)d2 >= ND2) continue;
        for (int kw = 0; kw < 3; kw++) { int d3 = o3 - 1 + kw; if ((unsigned)d3 >= ND3) continue;
          s += m[(d1*ND2 + d2)*ND3 + d3];
        } } }
    om[i] = (s > 0.f) ? 1.f : 0.f;
}

// ---------------- BN finalize: reduce NSC stat copies -> affine (2 stages/launch) ----------------
__global__ void k_finalize2(const float* __restrict__ SN0, const float* __restrict__ g0,
                            const float* __restrict__ b0, float* __restrict__ o0,
                            const float* __restrict__ SN1, const float* __restrict__ g1,
                            const float* __restrict__ b1, float* __restrict__ o1,
                            const float* __restrict__ nactN)
{
    const float* SN = blockIdx.x ? SN1 : SN0;
    const float* g  = blockIdx.x ? g1  : g0;
    const float* b  = blockIdx.x ? b1  : b0;
    float*       o  = blockIdx.x ? o1  : o0;
    int c = threadIdx.x;      // 64 threads = 1 wave
    float s1 = 0.f, s2 = 0.f;
    #pragma unroll 4
    for (int k = 0; k < NSC; k++){
        s1 += SN[k*128 + c];
        s2 += SN[k*128 + 64 + c];
    }
    float nn = nactN[c];
    #pragma unroll
    for (int off = 32; off > 0; off >>= 1) nn += __shfl_xor(nn, off);
    float mean = s1 / nn;
    float var  = s2 / nn - mean*mean;
    float inv  = rsqrtf(var + 1e-5f);
    float sc   = inv * g[c];
    o[c]      = sc;
    o[64 + c] = b[c] - mean*sc;
}

// ---------------- weight pre-pack: W[co][ci][tap] f32 -> Wt[kc][co][32] bf16 ----------------
__global__ void k_wprep(const float* __restrict__ W, unsigned short* __restrict__ Wt,
                        int CIN, int NT)
{
    int i = blockIdx.x*256 + threadIdx.x;
    int K = CIN*NT;
    if (i >= 64*K) return;
    int ksub = i & 31;
    int t = i >> 5;
    int co = t & 63;
    int kc = t >> 6;
    int nch = CIN >> 5;
    int tap = kc / nch;
    int ci  = (kc - tap*nch)*32 + ksub;
    Wt[i] = f2b(W[((size_t)co*CIN + ci)*NT + tap]);
}

// ---------------- x f32 [ci][sp] -> masked bf16 [sp][32] ----------------
__global__ void k_prep_x(const float* __restrict__ x, const float* __restrict__ m,
                         unsigned short* __restrict__ xt)
{
    __shared__ float t[64][33];
    int sp0 = blockIdx.x*64;
    int tid = threadIdx.x;
    int c = tid>>6, s = tid&63;
    float mm = m[sp0+s];
    #pragma unroll
    for (int r=0;r<8;r++){
        int ci = c + r*4;
        t[s][ci] = x[(size_t)ci*SP + sp0 + s]*mm;
    }
    __syncthreads();
    int sp = tid>>2, c0 = (tid&3)*8;
    unsigned short o[8];
    #pragma unroll
    for (int i=0;i<8;i++) o[i] = f2b(t[sp][c0+i]);
    uint4 pk;
    pk.x = o[0] | ((unsigned)o[1]<<16);
    pk.y = o[2] | ((unsigned)o[3]<<16);
    pk.z = o[4] | ((unsigned)o[5]<<16);
    pk.w = o[6] | ((unsigned)o[7]<<16);
    *reinterpret_cast<uint4*>(xt + (size_t)(sp0+sp)*32 + c0) = pk;
}

// ---------------- res_B combine ----------------
__global__ void k_resB(const unsigned short* __restrict__ hA, const unsigned short* __restrict__ hB,
                       const float* __restrict__ sA, const float* __restrict__ sB,
                       const float* __restrict__ m,
                       unsigned short* __restrict__ rbt, float* __restrict__ resf)
{
    __shared__ float t[64][65];
    __shared__ float ss[256];
    int tid = threadIdx.x;
    if (tid < 128){ ss[tid] = sA[tid]; ss[128+tid] = sB[tid]; }
    __syncthreads();
    int sp0 = blockIdx.x*64;
    int sp = tid>>2, c0 = (tid&3)*16;
    float mm = m[sp0+sp];
    const size_t base = (size_t)(sp0+sp)*64 + c0;
    uint4 a0 = *reinterpret_cast<const uint4*>(hA + base);
    uint4 a1 = *reinterpret_cast<const uint4*>(hA + base + 8);
    uint4 b0 = *reinterpret_cast<const uint4*>(hB + base);
    uint4 b1 = *reinterpret_cast<const uint4*>(hB + base + 8);
    unsigned ua[16] = {a0.x&0xffffu,a0.x>>16,a0.y&0xffffu,a0.y>>16,a0.z&0xffffu,a0.z>>16,a0.w&0xffffu,a0.w>>16,
                       a1.x&0xffffu,a1.x>>16,a1.y&0xffffu,a1.y>>16,a1.z&0xffffu,a1.z>>16,a1.w&0xffffu,a1.w>>16};
    unsigned ub[16] = {b0.x&0xffffu,b0.x>>16,b0.y&0xffffu,b0.y>>16,b0.z&0xffffu,b0.z>>16,b0.w&0xffffu,b0.w>>16,
                       b1.x&0xffffu,b1.x>>16,b1.y&0xffffu,b1.y>>16,b1.z&0xffffu,b1.z>>16,b1.w&0xffffu,b1.w>>16};
    unsigned short o[16];
    #pragma unroll
    for (int q=0;q<16;q++){
        int ci = c0+q;
        float v = (b2f(ua[q])*ss[ci] + ss[64+ci] + b2f(ub[q])*ss[128+ci] + ss[192+ci])*mm;
        t[sp][ci] = v;
        o[q] = f2b(v);
    }
    uint4 p0, p1;
    p0.x = o[0]|((unsigned)o[1]<<16);  p0.y = o[2]|((unsigned)o[3]<<16);
    p0.z = o[4]|((unsigned)o[5]<<16);  p0.w = o[6]|((unsigned)o[7]<<16);
    p1.x = o[8]|((unsigned)o[9]<<16);  p1.y = o[10]|((unsigned)o[11]<<16);
    p1.z = o[12]|((unsigned)o[13]<<16); p1.w = o[14]|((unsigned)o[15]<<16);
    *reinterpret_cast<uint4*>(rbt + base)     = p0;
    *reinterpret_cast<uint4*>(rbt + base + 8) = p1;
    __syncthreads();
    int ci = tid>>2, s0 = (tid&3)*16;
    #pragma unroll
    for (int kq=0;kq<4;kq++){
        float4 ov;
        ov.x = t[s0+4*kq+0][ci]; ov.y = t[s0+4*kq+1][ci];
        ov.z = t[s0+4*kq+2][ci]; ov.w = t[s0+4*kq+3][ci];
        *reinterpret_cast<float4*>(resf + (size_t)ci*SP + sp0 + s0 + 4*kq) = ov;
    }
}

// ---------------- MFMA conv: weights + data both in LDS ----------------
// KIND 0: taps (3,1,3) rows=d1 ; KIND 1: taps (1,3,3) rows=d2
// 512 thr, 16-out-row tile. Data buffer = 18 rows x 34 vox x 32 ch (ch-split for CIN64).
// Weight buffer = one ch-pass: [9 tap][64 co][32 k] = 36 KB. LDS total 76.5 KB -> 2 blk/CU.
template<int KIND, int CIN, bool HASAFF>
__launch_bounds__(512, 4)
__global__ void mconv8(const unsigned short* __restrict__ in,   // bf16 [vox][CIN]
                       const unsigned short* __restrict__ Wt,   // bf16 [kc][64co][32k]
                       const float* __restrict__ scsh,          // affine [128] (HASAFF)
                       const float* __restrict__ mstage,        // mask (HASAFF)
                       const float* __restrict__ mout,          // mask at output voxel
                       unsigned short* __restrict__ outb,       // bf16 [vox][64]
                       float* __restrict__ statsN)              // [NSC][128]
{
    constexpr int NPASS = CIN/32;
    constexpr int NR    = 18;
    constexpr int ROWB  = 34*32*2;     // 2176 B (32-ch row)
    extern __shared__ __align__(16) char smem[];
    char*  dat = smem;                  // NR*ROWB = 39168
    char*  Wl  = smem + NR*ROWB;        // 36864
    float* sst = (float*)(Wl + 36864);  // 512

    const int tid = threadIdx.x;       // 0..511 = 8 waves
    const int w = tid>>6, l = tid&63, g = l>>4, lj = l&15;

    int gi = (blockIdx.x & 7)*(gridDim.x>>3) + (blockIdx.x>>3);
    int z  = gi % 160;
    int r0 = (gi / 160)*16;

    if (tid < 128) sst[tid] = 0.f;

    // border zero slots (0 and 33) - survive pass overwrites (slots 1..32 only)
    for (int i = tid; i < NR*8; i += 512){
        int rr = i >> 3, rem = i & 7;
        int slot = (rem >= 4) ? 33 : 0;
        int c = rem & 3;
        int dst = rr*ROWB + slot*64 + c*16;
        dst ^= ((slot&3)<<4);
        *reinterpret_cast<uint4*>(dat + dst) = make_uint4(0,0,0,0);
    }

    // per-t constants
    int tb[4], ovox[4];
    float mm[4];
    #pragma unroll
    for (int t=0;t<4;t++){
        int rowb = 2*w + (t>>1);          // 0..15
        int o3   = (t&1)*16 + lj;
        tb[t] = rowb*ROWB + (o3*32 + g*8)*2;
        int o2r = r0 + rowb;
        ovox[t] = (KIND==0) ? ((o2r*ND2 + z)*ND3 + o3)
                            : ((z*ND2 + o2r)*ND3 + o3);
        mm[t] = mout[ovox[t]];
    }
    int swz[3];
    #pragma unroll
    for (int kw=0;kw<3;kw++) swz[kw] = ((lj+kw)&3)<<4;
    const int wread = lj*64 + g*16;

    f32x4 acc[4][4];
    #pragma unroll
    for (int a=0;a<4;a++)
        #pragma unroll
        for (int b=0;b<4;b++)
            #pragma unroll
            for (int q=0;q<4;q++) acc[a][b][q] = 0.f;

    // staging thread mapping (data): 128 threads per row, 4 rows per iter
    const int srow = tid>>7;             // 0..3
    const int sd3  = (tid>>2)&31;        // 0..31
    const int kc   = tid&3;              // 16B ch-chunk (8 ch)

    #pragma unroll 1
    for (int pass=0; pass<NPASS; pass++){
        __syncthreads();   // prev pass compute done (and sst/border init visible)

        // ---- stage weights: 9 taps x 4 KB, linear (reads are contiguous -> no swizzle)
        #pragma unroll
        for (int i=0;i<5;i++){
            int idx = i*512 + tid;
            if (idx < 2304){
                int tap = idx>>8, c = idx&255;
                uint4 wv = *reinterpret_cast<const uint4*>(
                    Wt + (size_t)(tap*NPASS + pass)*2048 + c*8);
                *reinterpret_cast<uint4*>(Wl + tap*4096 + c*16) = wv;
            }
        }

        // ---- stage data: 18 rows x 32 vox x 32 ch, slot-XOR swizzled
        float sc[8], sh[8];
        if (HASAFF){
            #pragma unroll
            for (int j=0;j<8;j++){
                int c = pass*32 + kc*8 + j;
                sc[j] = scsh[c]; sh[j] = scsh[64+c];
            }
        }
        uint4 v[5]; float mmr[5];
        #pragma unroll
        for (int i=0;i<5;i++){
            int rr = i*4 + srow;
            int rw = r0 - 1 + rr;
            v[i] = make_uint4(0,0,0,0); mmr[i] = 0.f;
            if (rr < NR && (unsigned)rw < 160u){
                int vox = (KIND==0) ? ((rw*ND2 + z)*ND3 + sd3)
                                    : ((z*ND2 + rw)*ND3 + sd3);
                v[i] = *reinterpret_cast<const uint4*>(in + (size_t)vox*CIN + pass*32 + kc*8);
                if (HASAFF) mmr[i] = mstage[vox];
            }
        }
        #pragma unroll
        for (int i=0;i<5;i++){
            int rr = i*4 + srow;
            if (rr >= NR) continue;
            uint4 vv = v[i];
            if (HASAFF){
                float mmv = mmr[i];
                unsigned us[8] = {vv.x&0xffffu,vv.x>>16,vv.y&0xffffu,vv.y>>16,
                                  vv.z&0xffffu,vv.z>>16,vv.w&0xffffu,vv.w>>16};
                unsigned short o[8];
                #pragma unroll
                for (int j=0;j<8;j++) o[j] = f2b((b2f(us[j])*sc[j]+sh[j])*mmv);
                vv.x = o[0]|((unsigned)o[1]<<16); vv.y = o[2]|((unsigned)o[3]<<16);
                vv.z = o[4]|((unsigned)o[5]<<16); vv.w = o[6]|((unsigned)o[7]<<16);
            }
            int dst = rr*ROWB + ((sd3+1)*64 + kc*16);
            dst ^= (((sd3+1)&3)<<4);
            *reinterpret_cast<uint4*>(dat + dst) = vv;
        }
        __syncthreads();

        // ---- compute: 9 taps, all operands from LDS
        #pragma unroll
        for (int tap=0; tap<9; tap++){
            const int kd = tap/3, kw = tap - kd*3;
            const char* wb = Wl + tap*4096 + wread;
            short8 pa[4];
            #pragma unroll
            for (int ct=0;ct<4;ct++) pa[ct] = *reinterpret_cast<const short8*>(wb + ct*1024);
            const int tapoff = kd*ROWB + kw*64;
            #pragma unroll
            for (int t=0;t<4;t++){
                int off = (tb[t] + tapoff) ^ swz[kw];
                short8 bv = *reinterpret_cast<const short8*>(dat + off);
                #pragma unroll
                for (int ct=0; ct<4; ct++)
                    acc[ct][t] = __builtin_amdgcn_mfma_f32_16x16x32_bf16(pa[ct], bv, acc[ct][t], 0,0,0);
            }
        }
    }

    // ---- epilogue
    #pragma unroll
    for (int ct=0;ct<4;ct++){
        float s1[4] = {0.f,0.f,0.f,0.f};
        float s2[4] = {0.f,0.f,0.f,0.f};
        #pragma unroll
        for (int t=0;t<4;t++){
            float vv[4];
            #pragma unroll
            for (int r=0;r<4;r++){
                float xv = acc[ct][t][r]*mm[t];
                xv = (xv >= 0.f) ? xv : 0.01f*xv;
                vv[r] = xv; s1[r] += xv; s2[r] += xv*xv;
            }
            unsigned lo = f2b(vv[0]) | ((unsigned)f2b(vv[1])<<16);
            unsigned hi = f2b(vv[2]) | ((unsigned)f2b(vv[3])<<16);
            *reinterpret_cast<uint2*>(outb + (size_t)ovox[t]*64 + ct*16 + g*4) = make_uint2(lo,hi);
        }
        #pragma unroll
        for (int r=0;r<4;r++){
            float a = s1[r], b = s2[r];
            a += __shfl_xor(a,1); b += __shfl_xor(b,1);
            a += __shfl_xor(a,2); b += __shfl_xor(b,2);
            a += __shfl_xor(a,4); b += __shfl_xor(b,4);
            a += __shfl_xor(a,8); b += __shfl_xor(b,8);
            if (lj == 0){
                atomicAdd(&sst[ct*16 + g*4 + r], a);
                atomicAdd(&sst[64 + ct*16 + g*4 + r], b);
            }
        }
    }
    __syncthreads();
    if (tid < 128){
        float* sg = statsN + (size_t)(blockIdx.x & (NSC-1))*128;
        atomicAdd(&sg[tid], sst[tid]);
    }
}

// ---------------- pool conv: round-6 structure + weights in LDS ----------------
__launch_bounds__(256, 2)
__global__ void mpool2(const unsigned short* __restrict__ in,   // bf16 [vox][64]
                       const unsigned short* __restrict__ Wt,   // bf16 [kc][64co][32k]
                       const float* __restrict__ mout,          // out_mask
                       float* __restrict__ outf)                // f32 [co][OSP]
{
    constexpr int ROWB = 34*64*2;    // 4352 (full 64-ch rows)
    extern __shared__ __align__(16) char smem[];
    char* dat = smem;                // 9*4352 = 39168
    char* Wl  = smem + 9*ROWB;       // 36864

    const int tid = threadIdx.x;
    const int w = tid>>6, l = tid&63, g = l>>4, lj = l&15;

    int gi = (blockIdx.x & 7)*(gridDim.x>>3) + (blockIdx.x>>3);
    int z  = gi % OD1;
    int r0 = (gi / OD1)*4;

    const int sd3 = tid>>3;
    const int k0  = (tid&7)*8;

    int swz[3];
    #pragma unroll
    for (int kw=0;kw<3;kw++) swz[kw] = ((lj+kw)&7)<<4;
    const int wread = lj*64 + g*16;

    // border zeros once (slots 0,33 survive row overwrites)
    for (int i = tid; i < 9*2*8; i += 256){
        int rr = i / 16;
        int rem = i - rr*16;
        int slot = (rem >= 8) ? 33 : 0;
        int kc16 = rem & 7;
        int dst = rr*ROWB + slot*128 + kc16*16;
        dst ^= ((slot&7)<<4);
        *reinterpret_cast<uint4*>(dat + dst) = make_uint4(0,0,0,0);
    }

    int tb2[2], ovx[2];
    float om[2];
    #pragma unroll
    for (int t=0;t<2;t++){
        int o3 = t*16 + lj;
        tb2[t] = (o3*64 + g*8)*2;
        ovx[t] = (z*OD2 + (r0 + w))*OD3 + o3;
        om[t]  = mout[ovx[t]];
    }
    f32x4 acc[4][2];
    #pragma unroll
    for (int a=0;a<4;a++)
        #pragma unroll
        for (int b=0;b<2;b++)
            #pragma unroll
            for (int q=0;q<4;q++) acc[a][b][q] = 0.f;

    const int rrb = 2*w;
    uint4 rv[9];

    #pragma unroll 1
    for (int kd=0; kd<3; kd++){
        // issue data loads for this plane (in flight across barrier)
        {
            int d1 = 2*z - 1 + kd;
            bool pok = ((unsigned)d1 < (unsigned)ND1);
            #pragma unroll
            for (int rr=0; rr<9; rr++){
                int d2 = 2*r0 - 1 + rr;
                rv[rr] = make_uint4(0,0,0,0);
                if (pok && ((unsigned)d2 < (unsigned)ND2)){
                    int vox = (d1*ND2 + d2)*ND3 + sd3;
                    rv[rr] = *reinterpret_cast<const uint4*>(in + (size_t)vox*64 + k0);
                }
            }
        }
        #pragma unroll 1
        for (int ch=0; ch<2; ch++){
            __syncthreads();   // prev compute done (protects data & W overwrite)
            if (ch == 0){
                #pragma unroll
                for (int rr=0; rr<9; rr++){
                    int dst = (rr*ROWB + (((sd3+1)*64 + k0)*2)) ^ (((sd3+1)&7)<<4);
                    *reinterpret_cast<uint4*>(dat + dst) = rv[rr];
                }
            }
            // stage weights for (kd, ch): 9 taps x 4 KB
            for (int i = tid; i < 2304; i += 256){
                int tap = i>>8, c = i&255;
                int kcg = (kd*9 + tap)*2 + ch;
                uint4 wv = *reinterpret_cast<const uint4*>(Wt + (size_t)kcg*2048 + c*8);
                *reinterpret_cast<uint4*>(Wl + tap*4096 + c*16) = wv;
            }
            __syncthreads();
            #pragma unroll
            for (int tap=0; tap<9; tap++){
                const int kh = tap/3, kw = tap - kh*3;
                const char* wb = Wl + tap*4096 + wread;
                short8 pa[4];
                #pragma unroll
                for (int ct=0;ct<4;ct++) pa[ct] = *reinterpret_cast<const short8*>(wb + ct*1024);
                const int tapoff = (rrb + kh)*ROWB + (kw*64 + ch*32)*2;
                #pragma unroll
                for (int t=0;t<2;t++){
                    int off = (tb2[t] + tapoff) ^ swz[kw];
                    short8 bv = *reinterpret_cast<const short8*>(dat + off);
                    #pragma unroll
                    for (int ct=0; ct<4; ct++)
                        acc[ct][t] = __builtin_amdgcn_mfma_f32_16x16x32_bf16(pa[ct], bv, acc[ct][t], 0,0,0);
                }
            }
        }
    }
    // epilogue
    #pragma unroll
    for (int t=0;t<2;t++){
        #pragma unroll
        for (int ct=0;ct<4;ct++){
            #pragma unroll
            for (int r=0;r<4;r++){
                int co = ct*16 + g*4 + r;
                outf[(size_t)co*OSP + ovx[t]] = acc[ct][t][r]*om[t];
            }
        }
    }
}

// ---------------- launch ----------------
extern "C" void kernel_launch(void* const* d_in, const int* in_sizes, int n_in,
                              void* d_out, int out_size, void* d_ws, size_t ws_size,
                              hipStream_t stream)
{
    const float* x      = (const float*)d_in[0];
    const void*  mraw   = d_in[1];
    const float* W_A1   = (const float*)d_in[2];
    const float* W_A2   = (const float*)d_in[3];
    const float* W_B1   = (const float*)d_in[4];
    const float* W_B2   = (const float*)d_in[5];
    const float* W_pool = (const float*)d_in[6];
    const float* g_A1 = (const float*)d_in[7],  *b_A1 = (const float*)d_in[8];
    const float* g_A2 = (const float*)d_in[9],  *b_A2 = (const float*)d_in[10];
    const float* g_B1 = (const float*)d_in[11], *b_B1 = (const float*)d_in[12];
    const float* g_B2 = (const float*)d_in[13], *b_B2 = (const float*)d_in[14];

    char* p = (char*)d_ws;
    float* m     = (float*)p; p += (size_t)SP*4;
    float* omask = (float*)p; p += (size_t)OSP*4;
    float* statsN= (float*)p; p += 4*NSC*128*4;
    float* scsh  = (float*)p; p += 4*128*4;
    float* nactN = (float*)p; p += NSC*4;
    int*   flag  = (int*)p;   p += 4;
    p += 252;
    unsigned short* WtA1 = (unsigned short*)p; p += 288*64*2;
    unsigned short* WtA2 = (unsigned short*)p; p += 576*64*2;
    unsigned short* WtB1 = (unsigned short*)p; p += 288*64*2;
    unsigned short* WtB2 = (unsigned short*)p; p += 576*64*2;
    unsigned short* WtP  = (unsigned short*)p; p += 1728*64*2;
    unsigned short* X = (unsigned short*)p; p += (size_t)SP*32*2;
    unsigned short* P = (unsigned short*)p; p += (size_t)SP*64*2;
    unsigned short* Q = (unsigned short*)p; p += (size_t)SP*64*2;
    unsigned short* R = (unsigned short*)p; p += (size_t)SP*64*2;

    float* down = (float*)d_out;                 // [64][OSP]
    float* resf = down + (size_t)CO*OSP;         // [64][SP]

    const int shmC = 18*(34*32*2) + 36864 + 512;     // 76544
    const int shmP = 9*(34*64*2) + 36864;            // 76032
    hipFuncSetAttribute((const void*)&mconv8<0,32,false>, hipFuncAttributeMaxDynamicSharedMemorySize, shmC);
    hipFuncSetAttribute((const void*)&mconv8<1,32,false>, hipFuncAttributeMaxDynamicSharedMemorySize, shmC);
    hipFuncSetAttribute((const void*)&mconv8<1,64,true>,  hipFuncAttributeMaxDynamicSharedMemorySize, shmC);
    hipFuncSetAttribute((const void*)&mconv8<0,64,true>,  hipFuncAttributeMaxDynamicSharedMemorySize, shmC);
    hipFuncSetAttribute((const void*)&mpool2, hipFuncAttributeMaxDynamicSharedMemorySize, shmP);

    hipMemsetAsync(statsN, 0, (4*NSC*128 + 4*128 + NSC)*4 + 4, stream);
    k_detect<<<256, 256, 0, stream>>>((const unsigned char*)mraw, flag);
    k_mask<<<SP/256, 256, 0, stream>>>(mraw, flag, m, nactN);
    k_outmask<<<OSP/256, 256, 0, stream>>>(m, omask);
    k_prep_x<<<SP/64, 256, 0, stream>>>(x, m, X);

    k_wprep<<<(64*288+255)/256, 256, 0, stream>>>(W_A1, WtA1, 32, 9);
    k_wprep<<<(64*576+255)/256, 256, 0, stream>>>(W_A2, WtA2, 64, 9);
    k_wprep<<<(64*288+255)/256, 256, 0, stream>>>(W_B1, WtB1, 32, 9);
    k_wprep<<<(64*576+255)/256, 256, 0, stream>>>(W_B2, WtB2, 64, 9);
    k_wprep<<<(64*1728+255)/256, 256, 0, stream>>>(W_pool, WtP, 64, 27);

    float* SA1 = statsN + 0*NSC*128;
    float* SA2 = statsN + 1*NSC*128;
    float* SB1 = statsN + 2*NSC*128;
    float* SB2 = statsN + 3*NSC*128;

    // stage 1: A1 and B1 (both read X). grid = 160 z x 10 (16-row tiles)
    mconv8<0,32,false><<<1600, 512, shmC, stream>>>(X, WtA1, nullptr, nullptr, m, P, SA1);
    mconv8<1,32,false><<<1600, 512, shmC, stream>>>(X, WtB1, nullptr, nullptr, m, Q, SB1);
    k_finalize2<<<2, 64, 0, stream>>>(SA1, g_A1, b_A1, scsh + 0,
                                      SB1, g_B1, b_B1, scsh + 256, nactN);
    // stage 2: A2 on BN_A1(P), B2 on BN_B1(Q)
    mconv8<1,64,true><<<1600, 512, shmC, stream>>>(P, WtA2, scsh + 0,   m, m, R, SA2);
    mconv8<0,64,true><<<1600, 512, shmC, stream>>>(Q, WtB2, scsh + 256, m, m, P, SB2);
    k_finalize2<<<2, 64, 0, stream>>>(SA2, g_A2, b_A2, scsh + 128,
                                      SB2, g_B2, b_B2, scsh + 384, nactN);
    // res_B combine -> Q (bf16 for pool) + resf (f32 output)
    k_resB<<<SP/64, 256, 0, stream>>>(R, P, scsh + 128, scsh + 384, m, Q, resf);
    // pool: 80 z x 20 (4-row tiles)
    mpool2<<<1600, 256, shmP, stream>>>(Q, WtP, omask, down);
}

// Round 10
// 827.597 us; speedup vs baseline: 1.1965x; 1.1965x over previous
//
#include <hip/hip_runtime.h>

static constexpr int ND1=160, ND2=160, ND3=32;
static constexpr int SP  = ND1*ND2*ND3;        // 819200
static constexpr int CO  = 64;
static constexpr int OD1=80, OD2=80, OD3=32;
static constexpr int OSP = OD1*OD2*OD3;        // 204800
static constexpr int NSC = 64;                 // stat copies (contention spread)

typedef __attribute__((ext_vector_type(8))) short  short8;
typedef __attribute__((ext_vector_type(4))) float  f32x4;

__device__ __forceinline__ float b2f(unsigned u){ return __uint_as_float(u<<16); }
__device__ __forceinline__ unsigned short f2b(float f){
    unsigned u = __float_as_uint(f);
    u += 0x7fffu + ((u>>16)&1u);
    return (unsigned short)(u>>16);
}
__device__ __forceinline__ void gload16(const void* g, void* l){
    __builtin_amdgcn_global_load_lds(
        (const __attribute__((address_space(1))) void*)g,
        (__attribute__((address_space(3))) void*)l, 16, 0, 0);
}

// ---------------- mask dtype detection ----------------
__global__ void k_detect(const unsigned char* __restrict__ mb, int* __restrict__ flag)
{
    __shared__ int lf;
    if (threadIdx.x == 0) lf = 0;
    __syncthreads();
    int f = 0;
    for (int i = blockIdx.x*256 + threadIdx.x; i < SP; i += gridDim.x*256) {
        unsigned char b = mb[i];
        if (b > 1) f |= 4;
        if (b != 0 && (i & 3)) f |= 1;
    }
    if (f) atomicOr(&lf, f);
    __syncthreads();
    if (threadIdx.x == 0 && lf) atomicOr(flag, lf);
}

__global__ void k_mask(const void* __restrict__ mraw, const int* __restrict__ flag,
                       float* __restrict__ m, float* __restrict__ nactN)
{
    int i = blockIdx.x*256 + threadIdx.x;
    int f = *flag;
    float v;
    if (f & 4)      v = (reinterpret_cast<const float*>(mraw)[i] != 0.f) ? 1.f : 0.f;
    else if (f & 1) v = (reinterpret_cast<const unsigned char*>(mraw)[i] != 0) ? 1.f : 0.f;
    else            v = (reinterpret_cast<const int*>(mraw)[i] != 0) ? 1.f : 0.f;
    m[i] = v;
    float s = v;
    #pragma unroll
    for (int off = 32; off > 0; off >>= 1) s += __shfl_xor(s, off);
    __shared__ float wsum[4];
    if ((threadIdx.x & 63) == 0) wsum[threadIdx.x >> 6] = s;
    __syncthreads();
    if (threadIdx.x == 0) atomicAdd(&nactN[blockIdx.x & (NSC-1)], wsum[0]+wsum[1]+wsum[2]+wsum[3]);
}

__global__ void k_outmask(const float* __restrict__ m, float* __restrict__ om)
{
    int i = blockIdx.x*256 + threadIdx.x;   // < OSP
    int o3 = i & 31; int t = i >> 5; int o2 = t % OD2; int o1 = t / OD2;
    float s = 0.f;
    for (int kd = 0; kd < 3; kd++) { int d1 = 2*o1 - 1 + kd; if ((unsigned)d1 >= ND1) continue;
      for (int kh = 0; kh < 3; kh++) { int d2 = 2*o2 - 1 + kh; if ((unsigned)d2 >= ND2) continue;
        for (int kw = 0; kw < 3; kw++) { int d3 = o3 - 1 + kw; if ((unsigned)d3 >= ND3) continue;
          s += m[(d1*ND2 + d2)*ND3 + d3];
        } } }
    om[i] = (s > 0.f) ? 1.f : 0.f;
}

// ---------------- BN finalize (2 stages/launch) ----------------
__global__ void k_finalize2(const float* __restrict__ SN0, const float* __restrict__ g0,
                            const float* __restrict__ b0, float* __restrict__ o0,
                            const float* __restrict__ SN1, const float* __restrict__ g1,
                            const float* __restrict__ b1, float* __restrict__ o1,
                            const float* __restrict__ nactN)
{
    const float* SN = blockIdx.x ? SN1 : SN0;
    const float* g  = blockIdx.x ? g1  : g0;
    const float* b  = blockIdx.x ? b1  : b0;
    float*       o  = blockIdx.x ? o1  : o0;
    int c = threadIdx.x;
    float s1 = 0.f, s2 = 0.f;
    #pragma unroll 4
    for (int k = 0; k < NSC; k++){
        s1 += SN[k*128 + c];
        s2 += SN[k*128 + 64 + c];
    }
    float nn = nactN[c];
    #pragma unroll
    for (int off = 32; off > 0; off >>= 1) nn += __shfl_xor(nn, off);
    float mean = s1 / nn;
    float var  = s2 / nn - mean*mean;
    float inv  = rsqrtf(var + 1e-5f);
    float sc   = inv * g[c];
    o[c]      = sc;
    o[64 + c] = b[c] - mean*sc;
}

// ---------------- weight pre-pack ----------------
__global__ void k_wprep(const float* __restrict__ W, unsigned short* __restrict__ Wt,
                        int CIN, int NT)
{
    int i = blockIdx.x*256 + threadIdx.x;
    int K = CIN*NT;
    if (i >= 64*K) return;
    int ksub = i & 31;
    int t = i >> 5;
    int co = t & 63;
    int kc = t >> 6;
    int nch = CIN >> 5;
    int tap = kc / nch;
    int ci  = (kc - tap*nch)*32 + ksub;
    Wt[i] = f2b(W[((size_t)co*CIN + ci)*NT + tap]);
}

// ---------------- x f32 [ci][sp] -> masked bf16 [sp][32] ----------------
__global__ void k_prep_x(const float* __restrict__ x, const float* __restrict__ m,
                         unsigned short* __restrict__ xt)
{
    __shared__ float t[64][33];
    int sp0 = blockIdx.x*64;
    int tid = threadIdx.x;
    int c = tid>>6, s = tid&63;
    float mm = m[sp0+s];
    #pragma unroll
    for (int r=0;r<8;r++){
        int ci = c + r*4;
        t[s][ci] = x[(size_t)ci*SP + sp0 + s]*mm;
    }
    __syncthreads();
    int sp = tid>>2, c0 = (tid&3)*8;
    unsigned short o[8];
    #pragma unroll
    for (int i=0;i<8;i++) o[i] = f2b(t[sp][c0+i]);
    uint4 pk;
    pk.x = o[0] | ((unsigned)o[1]<<16);
    pk.y = o[2] | ((unsigned)o[3]<<16);
    pk.z = o[4] | ((unsigned)o[5]<<16);
    pk.w = o[6] | ((unsigned)o[7]<<16);
    *reinterpret_cast<uint4*>(xt + (size_t)(sp0+sp)*32 + c0) = pk;
}

// ---------------- in-place BN affine + mask on bf16 [sp][64] ----------------
__global__ void k_affine(unsigned short* __restrict__ h, const float* __restrict__ scsh,
                         const float* __restrict__ m)
{
    __shared__ float ss[128];
    int tid = threadIdx.x;
    if (tid < 128) ss[tid] = scsh[tid];
    __syncthreads();
    int i = blockIdx.x*256 + tid;          // < SP*8
    int sp = i >> 3;
    int c0 = (i & 7) * 8;
    float mm = m[sp];
    uint4 pk = *reinterpret_cast<uint4*>(h + (size_t)sp*64 + c0);
    unsigned us[8] = {pk.x&0xffffu, pk.x>>16, pk.y&0xffffu, pk.y>>16,
                      pk.z&0xffffu, pk.z>>16, pk.w&0xffffu, pk.w>>16};
    unsigned short o[8];
    #pragma unroll
    for (int q=0;q<8;q++){
        float v = (b2f(us[q])*ss[c0+q] + ss[64+c0+q])*mm;
        o[q] = f2b(v);
    }
    uint4 po;
    po.x = o[0] | ((unsigned)o[1]<<16);
    po.y = o[2] | ((unsigned)o[3]<<16);
    po.z = o[4] | ((unsigned)o[5]<<16);
    po.w = o[6] | ((unsigned)o[7]<<16);
    *reinterpret_cast<uint4*>(h + (size_t)sp*64 + c0) = po;
}

// ---------------- res_B combine ----------------
__global__ void k_resB(const unsigned short* __restrict__ hA, const unsigned short* __restrict__ hB,
                       const float* __restrict__ sA, const float* __restrict__ sB,
                       const float* __restrict__ m,
                       unsigned short* __restrict__ rbt, float* __restrict__ resf)
{
    __shared__ float t[64][65];
    __shared__ float ss[256];
    int tid = threadIdx.x;
    if (tid < 128){ ss[tid] = sA[tid]; ss[128+tid] = sB[tid]; }
    __syncthreads();
    int sp0 = blockIdx.x*64;
    int sp = tid>>2, c0 = (tid&3)*16;
    float mm = m[sp0+sp];
    const size_t base = (size_t)(sp0+sp)*64 + c0;
    uint4 a0 = *reinterpret_cast<const uint4*>(hA + base);
    uint4 a1 = *reinterpret_cast<const uint4*>(hA + base + 8);
    uint4 b0 = *reinterpret_cast<const uint4*>(hB + base);
    uint4 b1 = *reinterpret_cast<const uint4*>(hB + base + 8);
    unsigned ua[16] = {a0.x&0xffffu,a0.x>>16,a0.y&0xffffu,a0.y>>16,a0.z&0xffffu,a0.z>>16,a0.w&0xffffu,a0.w>>16,
                       a1.x&0xffffu,a1.x>>16,a1.y&0xffffu,a1.y>>16,a1.z&0xffffu,a1.z>>16,a1.w&0xffffu,a1.w>>16};
    unsigned ub[16] = {b0.x&0xffffu,b0.x>>16,b0.y&0xffffu,b0.y>>16,b0.z&0xffffu,b0.z>>16,b0.w&0xffffu,b0.w>>16,
                       b1.x&0xffffu,b1.x>>16,b1.y&0xffffu,b1.y>>16,b1.z&0xffffu,b1.z>>16,b1.w&0xffffu,b1.w>>16};
    unsigned short o[16];
    #pragma unroll
    for (int q=0;q<16;q++){
        int ci = c0+q;
        float v = (b2f(ua[q])*ss[ci] + ss[64+ci] + b2f(ub[q])*ss[128+ci] + ss[192+ci])*mm;
        t[sp][ci] = v;
        o[q] = f2b(v);
    }
    uint4 p0, p1;
    p0.x = o[0]|((unsigned)o[1]<<16);  p0.y = o[2]|((unsigned)o[3]<<16);
    p0.z = o[4]|((unsigned)o[5]<<16);  p0.w = o[6]|((unsigned)o[7]<<16);
    p1.x = o[8]|((unsigned)o[9]<<16);  p1.y = o[10]|((unsigned)o[11]<<16);
    p1.z = o[12]|((unsigned)o[13]<<16); p1.w = o[14]|((unsigned)o[15]<<16);
    *reinterpret_cast<uint4*>(rbt + base)     = p0;
    *reinterpret_cast<uint4*>(rbt + base + 8) = p1;
    __syncthreads();
    int ci = tid>>2, s0 = (tid&3)*16;
    #pragma unroll
    for (int kq=0;kq<4;kq++){
        float4 ov;
        ov.x = t[s0+4*kq+0][ci]; ov.y = t[s0+4*kq+1][ci];
        ov.z = t[s0+4*kq+2][ci]; ov.w = t[s0+4*kq+3][ci];
        *reinterpret_cast<float4*>(resf + (size_t)ci*SP + sp0 + s0 + 4*kq) = ov;
    }
}

// ---------------- MFMA conv: round-6 structure + global_load_lds staging ----------------
// KIND 0: taps (3,1,3) rows=d1 ; KIND 1: taps (1,3,3) rows=d2
template<int KIND, int CIN>
__launch_bounds__(256, (CIN==32) ? 4 : 3)
__global__ void mconv9(const unsigned short* __restrict__ in,   // bf16 [vox][CIN] (pre-affined/masked)
                       const unsigned short* __restrict__ Wt,   // bf16 [kc][64co][32k]
                       const float* __restrict__ mout,          // mask at output voxel
                       unsigned short* __restrict__ outb,       // bf16 [vox][64]
                       float* __restrict__ statsN)              // [NSC][128]
{
    constexpr int NCH  = CIN/32;
    constexpr int NR   = 10;
    constexpr int VPB  = CIN*2;          // bytes per voxel
    constexpr int ROWB = 34*VPB;
    constexpr int SWZ  = (CIN==64) ? 7 : 3;
    constexpr int NSEG = (CIN==64) ? 4 : 2;      // 1024B wave-segments of interior
    __shared__ __align__(16) char lds[NR*ROWB];
    __shared__ float sst[128];

    const int tid = threadIdx.x;
    const int w = tid>>6, l = tid&63, g = l>>4, lj = l&15;

    int gi = (blockIdx.x & 7)*(gridDim.x>>3) + (blockIdx.x>>3);
    int z  = gi % 160;
    int r0 = (gi / 160)*8;

    if (tid < 128) sst[tid] = 0.f;

    // border zeros: slots 0 and 33 (linear; content is zero so swizzle irrelevant)
    for (int i = tid; i < NR*2*(VPB/16); i += 256){
        int per = VPB/16;
        int rr = i / (2*per);
        int rem = i - rr*2*per;
        int off = (rem < per) ? rem*16 : (33*VPB + (rem-per)*16);
        *reinterpret_cast<uint4*>(lds + rr*ROWB + off) = make_uint4(0,0,0,0);
    }

    // per-lane pre-swizzled source offsets (bytes) per 1024B segment
    int laneOff[NSEG];
    #pragma unroll
    for (int s=0;s<NSEG;s++){
        int Ds = s*1024 + l*16;
        int v  = 1 + Ds/VPB;
        int cl = (Ds>>4) & SWZ;
        int cs = cl ^ (v & SWZ);
        laneOff[s] = (v-1)*VPB + cs*16;
    }
    // stage: each wave handles rows w, w+4, w+8 via global_load_lds (dest linear)
    #pragma unroll
    for (int rr = w; rr < NR; rr += 4){
        int rw = r0 - 1 + rr;
        if ((unsigned)rw < 160u){
            int voxb = (KIND==0) ? ((rw*ND2 + z)*ND3) : ((z*ND2 + rw)*ND3);
            const char* gp = (const char*)in + (size_t)voxb*VPB;
            #pragma unroll
            for (int s=0;s<NSEG;s++)
                gload16(gp + laneOff[s], lds + rr*ROWB + VPB + s*1024);
        } else {
            #pragma unroll
            for (int s=0;s<NSEG;s++)
                *reinterpret_cast<uint4*>(lds + rr*ROWB + VPB + s*1024 + l*16) = make_uint4(0,0,0,0);
        }
    }

    // per-t constants (hoisted)
    int tb[4], ovox[4];
    float mm[4];
    #pragma unroll
    for (int t=0;t<4;t++){
        int rowb = w*2 + (t>>1);
        int o3   = (t&1)*16 + lj;
        tb[t] = rowb*ROWB + ((o3*CIN + g*8)*2);
        int o2r = r0 + rowb;
        ovox[t] = (KIND==0) ? ((o2r*ND2 + z)*ND3 + o3)
                            : ((z*ND2 + o2r)*ND3 + o3);
        mm[t] = mout[ovox[t]];
    }
    int swz[3];
    #pragma unroll
    for (int kw=0;kw<3;kw++) swz[kw] = ((lj+kw)&SWZ)<<4;
    const int woff = lj*32 + g*8;

    __syncthreads();     // drains vmcnt (global_load_lds) + lgkm

    f32x4 acc[4][4];
    #pragma unroll
    for (int a=0;a<4;a++)
        #pragma unroll
        for (int b=0;b<4;b++)
            #pragma unroll
            for (int q=0;q<4;q++) acc[a][b][q] = 0.f;

    short8 pa[2][4], pb[2][4];
    auto loadA = [&](int tap, int ch, int buf){
        const unsigned short* wp = Wt + (size_t)(tap*NCH+ch)*2048 + woff;
        #pragma unroll
        for (int ct=0;ct<4;ct++) pa[buf][ct] = *reinterpret_cast<const short8*>(wp + ct*512);
    };
    auto loadB = [&](int tap, int ch, int buf){
        const int kd = tap/3, kw = tap - kd*3;
        const int tapoff = kd*ROWB + (kw*CIN + ch*32)*2;
        #pragma unroll
        for (int t=0;t<4;t++){
            int off = (tb[t] + tapoff) ^ swz[kw];
            pb[buf][t] = *reinterpret_cast<const short8*>(lds + off);
        }
    };

    #pragma unroll 1
    for (int ch=0; ch<NCH; ch++){
        __syncthreads();          // lockstep -> weight L1 hits
        loadA(0, ch, 0); loadB(0, ch, 0);
        #pragma unroll
        for (int tap=0; tap<9; tap++){
            const int cb = tap&1, nb = (tap&1)^1;
            if (tap < 8){ loadA(tap+1, ch, nb); loadB(tap+1, ch, nb); }
            #pragma unroll
            for (int t=0;t<4;t++)
                #pragma unroll
                for (int ct=0; ct<4; ct++)
                    acc[ct][t] = __builtin_amdgcn_mfma_f32_16x16x32_bf16(pa[cb][ct], pb[cb][t], acc[ct][t], 0,0,0);
        }
    }

    // epilogue
    __syncthreads();
    #pragma unroll
    for (int ct=0;ct<4;ct++){
        float s1[4] = {0.f,0.f,0.f,0.f};
        float s2[4] = {0.f,0.f,0.f,0.f};
        #pragma unroll
        for (int t=0;t<4;t++){
            float v[4];
            #pragma unroll
            for (int r=0;r<4;r++){
                float xv = acc[ct][t][r]*mm[t];
                xv = (xv >= 0.f) ? xv : 0.01f*xv;
                v[r] = xv; s1[r] += xv; s2[r] += xv*xv;
            }
            unsigned lo = f2b(v[0]) | ((unsigned)f2b(v[1])<<16);
            unsigned hi = f2b(v[2]) | ((unsigned)f2b(v[3])<<16);
            *reinterpret_cast<uint2*>(outb + (size_t)ovox[t]*64 + ct*16 + g*4) = make_uint2(lo,hi);
        }
        #pragma unroll
        for (int r=0;r<4;r++){
            float a = s1[r], b = s2[r];
            a += __shfl_xor(a,1); b += __shfl_xor(b,1);
            a += __shfl_xor(a,2); b += __shfl_xor(b,2);
            a += __shfl_xor(a,4); b += __shfl_xor(b,4);
            a += __shfl_xor(a,8); b += __shfl_xor(b,8);
            if (lj == 0){
                atomicAdd(&sst[ct*16 + g*4 + r], a);
                atomicAdd(&sst[64 + ct*16 + g*4 + r], b);
            }
        }
    }
    __syncthreads();
    if (tid < 128){
        float* sg = statsN + (size_t)(blockIdx.x & (NSC-1))*128;
        atomicAdd(&sg[tid], sst[tid]);
    }
}

// ---------------- pool conv (round-6 known-good) ----------------
__launch_bounds__(256, 4)
__global__ void mpool(const unsigned short* __restrict__ in,   // bf16 [vox][64]
                      const unsigned short* __restrict__ Wt,   // bf16 [kc][64co][32k]
                      const float* __restrict__ mout,          // out_mask
                      float* __restrict__ outf)                // f32 [co][OSP]
{
    constexpr int ROWB = 34*64*2;
    __shared__ __align__(16) char lds[9*ROWB];

    const int tid = threadIdx.x;
    const int w = tid>>6, l = tid&63, g = l>>4, lj = l&15;

    int gi = (blockIdx.x & 7)*(gridDim.x>>3) + (blockIdx.x>>3);
    int z  = gi % OD1;
    int r0 = (gi / OD1)*4;

    const int sd3 = tid>>3;
    const int k0  = (tid&7)*8;

    int swz[3];
    #pragma unroll
    for (int kw=0;kw<3;kw++) swz[kw] = ((lj+kw)&7)<<4;
    const int woff = lj*32 + g*8;

    for (int i = tid; i < 9*2*8; i += 256){
        int rr = i / 16;
        int rem = i - rr*16;
        int slot = (rem >= 8) ? 33 : 0;
        int kc16 = rem & 7;
        int dst = rr*ROWB + slot*128 + kc16*16;
        dst ^= ((slot&7)<<4);
        *reinterpret_cast<uint4*>(lds + dst) = make_uint4(0,0,0,0);
    }

    int tb2[2], ovx[2];
    float om[2];
    #pragma unroll
    for (int t=0;t<2;t++){
        int o3 = t*16 + lj;
        tb2[t] = (o3*64 + g*8)*2;
        ovx[t] = (z*OD2 + (r0 + w))*OD3 + o3;
        om[t]  = mout[ovx[t]];
    }
    f32x4 acc[4][2];
    #pragma unroll
    for (int a=0;a<4;a++)
        #pragma unroll
        for (int b=0;b<2;b++)
            #pragma unroll
            for (int q=0;q<4;q++) acc[a][b][q] = 0.f;

    short8 pa[2][4], pb[2][2];
    const int rrb = 2*w;

    uint4 rv[9];
    auto issue_plane = [&](int kd, uint4 (&dst)[9]){
        int d1 = 2*z - 1 + kd;
        bool pok = ((unsigned)d1 < (unsigned)ND1);
        #pragma unroll
        for (int rr=0; rr<9; rr++){
            int d2 = 2*r0 - 1 + rr;
            dst[rr] = make_uint4(0,0,0,0);
            if (pok && ((unsigned)d2 < (unsigned)ND2)){
                int vox = (d1*ND2 + d2)*ND3 + sd3;
                dst[rr] = *reinterpret_cast<const uint4*>(in + (size_t)vox*64 + k0);
            }
        }
    };

    #pragma unroll 1
    for (int kd=0; kd<3; kd++){
        issue_plane(kd, rv);
        __syncthreads();
        #pragma unroll
        for (int rr=0; rr<9; rr++){
            int dst = (rr*ROWB + (((sd3+1)*64 + k0)*2)) ^ (((sd3+1)&7)<<4);
            *reinterpret_cast<uint4*>(lds + dst) = rv[rr];
        }
        __syncthreads();

        auto loadA2 = [&](int tap, int ch, int buf){
            const int kh = tap/3, kw = tap - kh*3;
            const int kc = ((kd*3+kh)*3+kw)*2 + ch;
            const unsigned short* wp = Wt + (size_t)kc*2048 + woff;
            #pragma unroll
            for (int ct=0;ct<4;ct++) pa[buf][ct] = *reinterpret_cast<const short8*>(wp + ct*512);
        };
        auto loadB2 = [&](int tap, int ch, int buf){
            const int kh = tap/3, kw = tap - kh*3;
            const int tapoff = (rrb + kh)*ROWB + (kw*64 + ch*32)*2;
            #pragma unroll
            for (int t=0;t<2;t++){
                int off = (tb2[t] + tapoff) ^ swz[kw];
                pb[buf][t] = *reinterpret_cast<const short8*>(lds + off);
            }
        };

        #pragma unroll 1
        for (int ch=0; ch<2; ch++){
            loadA2(0, ch, 0); loadB2(0, ch, 0);
            #pragma unroll
            for (int tap=0; tap<9; tap++){
                const int cb = tap&1, nb = (tap&1)^1;
                if (tap < 8){ loadA2(tap+1, ch, nb); loadB2(tap+1, ch, nb); }
                #pragma unroll
                for (int t=0;t<2;t++)
                    #pragma unroll
                    for (int ct=0; ct<4; ct++)
                        acc[ct][t] = __builtin_amdgcn_mfma_f32_16x16x32_bf16(pa[cb][ct], pb[cb][t], acc[ct][t], 0,0,0);
            }
        }
    }
    #pragma unroll
    for (int t=0;t<2;t++){
        #pragma unroll
        for (int ct=0;ct<4;ct++){
            #pragma unroll
            for (int r=0;r<4;r++){
                int co = ct*16 + g*4 + r;
                outf[(size_t)co*OSP + ovx[t]] = acc[ct][t][r]*om[t];
            }
        }
    }
}

// ---------------- launch ----------------
extern "C" void kernel_launch(void* const* d_in, const int* in_sizes, int n_in,
                              void* d_out, int out_size, void* d_ws, size_t ws_size,
                              hipStream_t stream)
{
    const float* x      = (const float*)d_in[0];
    const void*  mraw   = d_in[1];
    const float* W_A1   = (const float*)d_in[2];
    const float* W_A2   = (const float*)d_in[3];
    const float* W_B1   = (const float*)d_in[4];
    const float* W_B2   = (const float*)d_in[5];
    const float* W_pool = (const float*)d_in[6];
    const float* g_A1 = (const float*)d_in[7],  *b_A1 = (const float*)d_in[8];
    const float* g_A2 = (const float*)d_in[9],  *b_A2 = (const float*)d_in[10];
    const float* g_B1 = (const float*)d_in[11], *b_B1 = (const float*)d_in[12];
    const float* g_B2 = (const float*)d_in[13], *b_B2 = (const float*)d_in[14];

    char* p = (char*)d_ws;
    float* m     = (float*)p; p += (size_t)SP*4;
    float* omask = (float*)p; p += (size_t)OSP*4;
    float* statsN= (float*)p; p += 4*NSC*128*4;
    float* scsh  = (float*)p; p += 4*128*4;
    float* nactN = (float*)p; p += NSC*4;
    int*   flag  = (int*)p;   p += 4;
    p += 252;
    unsigned short* WtA1 = (unsigned short*)p; p += 288*64*2;
    unsigned short* WtA2 = (unsigned short*)p; p += 576*64*2;
    unsigned short* WtB1 = (unsigned short*)p; p += 288*64*2;
    unsigned short* WtB2 = (unsigned short*)p; p += 576*64*2;
    unsigned short* WtP  = (unsigned short*)p; p += 1728*64*2;
    unsigned short* X = (unsigned short*)p; p += (size_t)SP*32*2;
    unsigned short* P = (unsigned short*)p; p += (size_t)SP*64*2;
    unsigned short* Q = (unsigned short*)p; p += (size_t)SP*64*2;
    unsigned short* R = (unsigned short*)p; p += (size_t)SP*64*2;

    float* down = (float*)d_out;                 // [64][OSP]
    float* resf = down + (size_t)CO*OSP;         // [64][SP]

    hipMemsetAsync(statsN, 0, (4*NSC*128 + 4*128 + NSC)*4 + 4, stream);
    k_detect<<<256, 256, 0, stream>>>((const unsigned char*)mraw, flag);
    k_mask<<<SP/256, 256, 0, stream>>>(mraw, flag, m, nactN);
    k_outmask<<<OSP/256, 256, 0, stream>>>(m, omask);
    k_prep_x<<<SP/64, 256, 0, stream>>>(x, m, X);

    k_wprep<<<(64*288+255)/256, 256, 0, stream>>>(W_A1, WtA1, 32, 9);
    k_wprep<<<(64*576+255)/256, 256, 0, stream>>>(W_A2, WtA2, 64, 9);
    k_wprep<<<(64*288+255)/256, 256, 0, stream>>>(W_B1, WtB1, 32, 9);
    k_wprep<<<(64*576+255)/256, 256, 0, stream>>>(W_B2, WtB2, 64, 9);
    k_wprep<<<(64*1728+255)/256, 256, 0, stream>>>(W_pool, WtP, 64, 27);

    float* SA1 = statsN + 0*NSC*128;
    float* SA2 = statsN + 1*NSC*128;
    float* SB1 = statsN + 2*NSC*128;
    float* SB2 = statsN + 3*NSC*128;

    // stage 1: A1 and B1 (both read X)
    mconv9<0,32><<<3200, 256, 0, stream>>>(X, WtA1, m, P, SA1);
    mconv9<1,32><<<3200, 256, 0, stream>>>(X, WtB1, m, Q, SB1);
    k_finalize2<<<2, 64, 0, stream>>>(SA1, g_A1, b_A1, scsh + 0,
                                      SB1, g_B1, b_B1, scsh + 256, nactN);
    // affine pre-pass: P' = BN_A1(P)*m, Q' = BN_B1(Q)*m
    k_affine<<<SP*8/256, 256, 0, stream>>>(P, scsh + 0, m);
    k_affine<<<SP*8/256, 256, 0, stream>>>(Q, scsh + 256, m);
    // stage 2: A2 on P', B2 on Q'
    mconv9<1,64><<<3200, 256, 0, stream>>>(P, WtA2, m, R, SA2);
    mconv9<0,64><<<3200, 256, 0, stream>>>(Q, WtB2, m, P, SB2);
    k_finalize2<<<2, 64, 0, stream>>>(SA2, g_A2, b_A2, scsh + 128,
                                      SB2, g_B2, b_B2, scsh + 384, nactN);
    // res_B combine -> Q (bf16 for pool) + resf (f32 output)
    k_resB<<<SP/64, 256, 0, stream>>>(R, P, scsh + 128, scsh + 384, m, Q, resf);
    // pool
    mpool<<<1600, 256, 0, stream>>>(Q, WtP, omask, down);
}

// Round 11
// 674.168 us; speedup vs baseline: 1.4688x; 1.2276x over previous
//
#include <hip/hip_runtime.h>

static constexpr int ND1=160, ND2=160, ND3=32;
static constexpr int SP  = ND1*ND2*ND3;        // 819200
static constexpr int CO  = 64;
static constexpr int OD1=80, OD2=80, OD3=32;
static constexpr int OSP = OD1*OD2*OD3;        // 204800
static constexpr int NSC = 64;                 // stat copies (contention spread)

typedef __attribute__((ext_vector_type(8))) short  short8;
typedef __attribute__((ext_vector_type(4))) float  f32x4;

__device__ __forceinline__ float b2f(unsigned u){ return __uint_as_float(u<<16); }
__device__ __forceinline__ unsigned short f2b(float f){
    unsigned u = __float_as_uint(f);
    u += 0x7fffu + ((u>>16)&1u);
    return (unsigned short)(u>>16);
}

// ---------------- mask dtype detection ----------------
__global__ void k_detect(const unsigned char* __restrict__ mb, int* __restrict__ flag)
{
    __shared__ int lf;
    if (threadIdx.x == 0) lf = 0;
    __syncthreads();
    int f = 0;
    for (int i = blockIdx.x*256 + threadIdx.x; i < SP; i += gridDim.x*256) {
        unsigned char b = mb[i];
        if (b > 1) f |= 4;
        if (b != 0 && (i & 3)) f |= 1;
    }
    if (f) atomicOr(&lf, f);
    __syncthreads();
    if (threadIdx.x == 0 && lf) atomicOr(flag, lf);
}

__global__ void k_mask(const void* __restrict__ mraw, const int* __restrict__ flag,
                       float* __restrict__ m, float* __restrict__ nactN)
{
    int i = blockIdx.x*256 + threadIdx.x;
    int f = *flag;
    float v;
    if (f & 4)      v = (reinterpret_cast<const float*>(mraw)[i] != 0.f) ? 1.f : 0.f;
    else if (f & 1) v = (reinterpret_cast<const unsigned char*>(mraw)[i] != 0) ? 1.f : 0.f;
    else            v = (reinterpret_cast<const int*>(mraw)[i] != 0) ? 1.f : 0.f;
    m[i] = v;
    float s = v;
    #pragma unroll
    for (int off = 32; off > 0; off >>= 1) s += __shfl_xor(s, off);
    __shared__ float wsum[4];
    if ((threadIdx.x & 63) == 0) wsum[threadIdx.x >> 6] = s;
    __syncthreads();
    if (threadIdx.x == 0) atomicAdd(&nactN[blockIdx.x & (NSC-1)], wsum[0]+wsum[1]+wsum[2]+wsum[3]);
}

__global__ void k_outmask(const float* __restrict__ m, float* __restrict__ om)
{
    int i = blockIdx.x*256 + threadIdx.x;   // < OSP
    int o3 = i & 31; int t = i >> 5; int o2 = t % OD2; int o1 = t / OD2;
    float s = 0.f;
    for (int kd = 0; kd < 3; kd++) { int d1 = 2*o1 - 1 + kd; if ((unsigned)d1 >= ND1) continue;
      for (int kh = 0; kh < 3; kh++) { int d2 = 2*o2 - 1 + kh; if ((unsigned)d2 >= ND2) continue;
        for (int kw = 0; kw < 3; kw++) { int d3 = o3 - 1 + kw; if ((unsigned)d3 >= ND3) continue;
          s += m[(d1*ND2 + d2)*ND3 + d3];
        } } }
    om[i] = (s > 0.f) ? 1.f : 0.f;
}

// ---------------- BN finalize (2 stages/launch) ----------------
__global__ void k_finalize2(const float* __restrict__ SN0, const float* __restrict__ g0,
                            const float* __restrict__ b0, float* __restrict__ o0,
                            const float* __restrict__ SN1, const float* __restrict__ g1,
                            const float* __restrict__ b1, float* __restrict__ o1,
                            const float* __restrict__ nactN)
{
    const float* SN = blockIdx.x ? SN1 : SN0;
    const float* g  = blockIdx.x ? g1  : g0;
    const float* b  = blockIdx.x ? b1  : b0;
    float*       o  = blockIdx.x ? o1  : o0;
    int c = threadIdx.x;
    float s1 = 0.f, s2 = 0.f;
    #pragma unroll 4
    for (int k = 0; k < NSC; k++){
        s1 += SN[k*128 + c];
        s2 += SN[k*128 + 64 + c];
    }
    float nn = nactN[c];
    #pragma unroll
    for (int off = 32; off > 0; off >>= 1) nn += __shfl_xor(nn, off);
    float mean = s1 / nn;
    float var  = s2 / nn - mean*mean;
    float inv  = rsqrtf(var + 1e-5f);
    float sc   = inv * g[c];
    o[c]      = sc;
    o[64 + c] = b[c] - mean*sc;
}

// ---------------- weight pre-pack ----------------
__global__ void k_wprep(const float* __restrict__ W, unsigned short* __restrict__ Wt,
                        int CIN, int NT)
{
    int i = blockIdx.x*256 + threadIdx.x;
    int K = CIN*NT;
    if (i >= 64*K) return;
    int ksub = i & 31;
    int t = i >> 5;
    int co = t & 63;
    int kc = t >> 6;
    int nch = CIN >> 5;
    int tap = kc / nch;
    int ci  = (kc - tap*nch)*32 + ksub;
    Wt[i] = f2b(W[((size_t)co*CIN + ci)*NT + tap]);
}

// ---------------- x f32 [ci][sp] -> masked bf16 [sp][32] ----------------
__global__ void k_prep_x(const float* __restrict__ x, const float* __restrict__ m,
                         unsigned short* __restrict__ xt)
{
    __shared__ float t[64][33];
    int sp0 = blockIdx.x*64;
    int tid = threadIdx.x;
    int c = tid>>6, s = tid&63;
    float mm = m[sp0+s];
    #pragma unroll
    for (int r=0;r<8;r++){
        int ci = c + r*4;
        t[s][ci] = x[(size_t)ci*SP + sp0 + s]*mm;
    }
    __syncthreads();
    int sp = tid>>2, c0 = (tid&3)*8;
    unsigned short o[8];
    #pragma unroll
    for (int i=0;i<8;i++) o[i] = f2b(t[sp][c0+i]);
    uint4 pk;
    pk.x = o[0] | ((unsigned)o[1]<<16);
    pk.y = o[2] | ((unsigned)o[3]<<16);
    pk.z = o[4] | ((unsigned)o[5]<<16);
    pk.w = o[6] | ((unsigned)o[7]<<16);
    *reinterpret_cast<uint4*>(xt + (size_t)(sp0+sp)*32 + c0) = pk;
}

// ---------------- res_B combine ----------------
__global__ void k_resB(const unsigned short* __restrict__ hA, const unsigned short* __restrict__ hB,
                       const float* __restrict__ sA, const float* __restrict__ sB,
                       const float* __restrict__ m,
                       unsigned short* __restrict__ rbt, float* __restrict__ resf)
{
    __shared__ float t[64][65];
    __shared__ float ss[256];
    int tid = threadIdx.x;
    if (tid < 128){ ss[tid] = sA[tid]; ss[128+tid] = sB[tid]; }
    __syncthreads();
    int sp0 = blockIdx.x*64;
    int sp = tid>>2, c0 = (tid&3)*16;
    float mm = m[sp0+sp];
    const size_t base = (size_t)(sp0+sp)*64 + c0;
    uint4 a0 = *reinterpret_cast<const uint4*>(hA + base);
    uint4 a1 = *reinterpret_cast<const uint4*>(hA + base + 8);
    uint4 b0 = *reinterpret_cast<const uint4*>(hB + base);
    uint4 b1 = *reinterpret_cast<const uint4*>(hB + base + 8);
    unsigned ua[16] = {a0.x&0xffffu,a0.x>>16,a0.y&0xffffu,a0.y>>16,a0.z&0xffffu,a0.z>>16,a0.w&0xffffu,a0.w>>16,
                       a1.x&0xffffu,a1.x>>16,a1.y&0xffffu,a1.y>>16,a1.z&0xffffu,a1.z>>16,a1.w&0xffffu,a1.w>>16};
    unsigned ub[16] = {b0.x&0xffffu,b0.x>>16,b0.y&0xffffu,b0.y>>16,b0.z&0xffffu,b0.z>>16,b0.w&0xffffu,b0.w>>16,
                       b1.x&0xffffu,b1.x>>16,b1.y&0xffffu,b1.y>>16,b1.z&0xffffu,b1.z>>16,b1.w&0xffffu,b1.w>>16};
    unsigned short o[16];
    #pragma unroll
    for (int q=0;q<16;q++){
        int ci = c0+q;
        float v = (b2f(ua[q])*ss[ci] + ss[64+ci] + b2f(ub[q])*ss[128+ci] + ss[192+ci])*mm;
        t[sp][ci] = v;
        o[q] = f2b(v);
    }
    uint4 p0, p1;
    p0.x = o[0]|((unsigned)o[1]<<16);  p0.y = o[2]|((unsigned)o[3]<<16);
    p0.z = o[4]|((unsigned)o[5]<<16);  p0.w = o[6]|((unsigned)o[7]<<16);
    p1.x = o[8]|((unsigned)o[9]<<16);  p1.y = o[10]|((unsigned)o[11]<<16);
    p1.z = o[12]|((unsigned)o[13]<<16); p1.w = o[14]|((unsigned)o[15]<<16);
    *reinterpret_cast<uint4*>(rbt + base)     = p0;
    *reinterpret_cast<uint4*>(rbt + base + 8) = p1;
    __syncthreads();
    int ci = tid>>2, s0 = (tid&3)*16;
    #pragma unroll
    for (int kq=0;kq<4;kq++){
        float4 ov;
        ov.x = t[s0+4*kq+0][ci]; ov.y = t[s0+4*kq+1][ci];
        ov.z = t[s0+4*kq+2][ci]; ov.w = t[s0+4*kq+3][ci];
        *reinterpret_cast<float4*>(resf + (size_t)ci*SP + sp0 + s0 + 4*kq) = ov;
    }
}

// ---------------- MFMA conv: weights in REGISTERS, pure ds_read+MFMA inner loop ----------------
// KIND 0: taps (3,1,3) rows=d1 ; KIND 1: taps (1,3,3) rows=d2
// Wave w: co-half h=w&1 (cts 2h,2h+1), row-group rg=w>>1 (rows rg*4..rg*4+3).
// pa[NKC][2] preloaded once (144 VGPR for CIN64); inner loop = 8 ds_read + 16 MFMA per kc.
template<int KIND, int CIN, bool HASAFF>
__launch_bounds__(256, (CIN==32) ? 3 : 2)
__global__ void mconv10(const unsigned short* __restrict__ in,   // bf16 [vox][CIN]
                        const unsigned short* __restrict__ Wt,   // bf16 [kc][64co][32k]
                        const float* __restrict__ scsh,          // affine [128] (HASAFF)
                        const float* __restrict__ mstage,        // mask (HASAFF)
                        const float* __restrict__ mout,          // mask at output voxel
                        unsigned short* __restrict__ outb,       // bf16 [vox][64]
                        float* __restrict__ statsN)              // [NSC][128]
{
    constexpr int NCH  = CIN/32;
    constexpr int NKC  = NCH*9;
    constexpr int NR   = 10;
    constexpr int ROWB = 34*CIN*2;
    constexpr int SWZ  = (CIN==64) ? 7 : 3;
    __shared__ __align__(16) char lds[NR*ROWB];
    __shared__ float sst[128];

    const int tid = threadIdx.x;
    const int w = tid>>6, l = tid&63, g = l>>4, lj = l&15;
    const int h = w&1, rg = w>>1;

    int gi = (blockIdx.x & 7)*(gridDim.x>>3) + (blockIdx.x>>3);
    int z  = gi % 160;
    int r0 = (gi / 160)*8;

    if (tid < 128) sst[tid] = 0.f;

    const int sd3 = tid>>3;              // 0..31
    const int k0  = (tid&7)*(CIN/8);     // 8 ch (CIN64) / 4 ch (CIN32)

    float sc[8], sh[8];
    if (HASAFF){
        #pragma unroll
        for (int j=0;j<8;j++){ sc[j]=scsh[k0+j]; sh[j]=scsh[64+k0+j]; }
    }

    // border zero slots (0 and 33)
    for (int i = tid; i < NR*2*(CIN/8); i += 256){
        int per = CIN/8;
        int rr = i / (2*per);
        int rem = i - rr*2*per;
        int slot = (rem >= per) ? 33 : 0;
        int kc16 = (rem >= per) ? (rem - per) : rem;
        int dst = rr*ROWB + slot*CIN*2 + kc16*16;
        dst ^= ((slot&SWZ)<<4);
        *reinterpret_cast<uint4*>(lds + dst) = make_uint4(0,0,0,0);
    }

    // ---- stage full-CIN rows (round-6 batched path) ----
    if (CIN==64){
        uint4 v[NR]; float mmr[NR];
        #pragma unroll
        for (int rr=0; rr<NR; rr++){
            int rw = r0 - 1 + rr;
            v[rr] = make_uint4(0,0,0,0); mmr[rr] = 0.f;
            if ((unsigned)rw < 160u){
                int vox = (KIND==0) ? ((rw*ND2 + z)*ND3 + sd3)
                                    : ((z*ND2 + rw)*ND3 + sd3);
                v[rr] = *reinterpret_cast<const uint4*>(in + (size_t)vox*CIN + k0);
                if (HASAFF) mmr[rr] = mstage[vox];
            }
        }
        #pragma unroll
        for (int rr=0; rr<NR; rr++){
            uint4 vv = v[rr];
            if (HASAFF){
                float mm = mmr[rr];
                unsigned us[8] = {vv.x&0xffffu,vv.x>>16,vv.y&0xffffu,vv.y>>16,
                                  vv.z&0xffffu,vv.z>>16,vv.w&0xffffu,vv.w>>16};
                unsigned short o[8];
                #pragma unroll
                for (int j=0;j<8;j++) o[j] = f2b((b2f(us[j])*sc[j]+sh[j])*mm);
                vv.x = o[0]|((unsigned)o[1]<<16); vv.y = o[2]|((unsigned)o[3]<<16);
                vv.z = o[4]|((unsigned)o[5]<<16); vv.w = o[6]|((unsigned)o[7]<<16);
            }
            int dst = (rr*ROWB + (((sd3+1)*CIN + k0)*2)) ^ (((sd3+1)&SWZ)<<4);
            *reinterpret_cast<uint4*>(lds + dst) = vv;
        }
    } else {
        uint2 v[NR];
        #pragma unroll
        for (int rr=0; rr<NR; rr++){
            int rw = r0 - 1 + rr;
            v[rr] = make_uint2(0,0);
            if ((unsigned)rw < 160u){
                int vox = (KIND==0) ? ((rw*ND2 + z)*ND3 + sd3)
                                    : ((z*ND2 + rw)*ND3 + sd3);
                v[rr] = *reinterpret_cast<const uint2*>(in + (size_t)vox*CIN + k0);
            }
        }
        #pragma unroll
        for (int rr=0; rr<NR; rr++){
            int dst = (rr*ROWB + (((sd3+1)*CIN + k0)*2)) ^ (((sd3+1)&SWZ)<<4);
            *reinterpret_cast<uint2*>(lds + dst) = v[rr];
        }
    }

    // ---- preload ALL weight fragments for this wave's co-half (stays in VGPRs) ----
    short8 pa[NKC][2];
    {
        const unsigned short* wb = Wt + (size_t)(h*32)*32 + lj*32 + g*8;
        #pragma unroll
        for (int kc=0; kc<NKC; kc++){
            pa[kc][0] = *reinterpret_cast<const short8*>(wb + (size_t)kc*2048);
            pa[kc][1] = *reinterpret_cast<const short8*>(wb + (size_t)kc*2048 + 512);
        }
    }

    // ---- per-tile constants (8 spatial tiles per wave) ----
    int tb[8], ovox[8];
    float mm[8];
    #pragma unroll
    for (int t=0;t<8;t++){
        int rowb = rg*4 + (t>>1);         // 0..7
        int o3   = (t&1)*16 + lj;
        tb[t] = rowb*ROWB + ((o3*CIN + g*8)*2);
        int o2r = r0 + rowb;
        ovox[t] = (KIND==0) ? ((o2r*ND2 + z)*ND3 + o3)
                            : ((z*ND2 + o2r)*ND3 + o3);
        mm[t] = mout[ovox[t]];
    }
    int swz[3];
    #pragma unroll
    for (int kw=0;kw<3;kw++) swz[kw] = ((lj+kw)&SWZ)<<4;

    __syncthreads();

    f32x4 acc[2][8];
    #pragma unroll
    for (int c=0;c<2;c++)
        #pragma unroll
        for (int t=0;t<8;t++)
            #pragma unroll
            for (int q=0;q<4;q++) acc[c][t][q] = 0.f;

    // ---- compute: fully unrolled, zero global loads, zero barriers ----
    #pragma unroll
    for (int ch=0; ch<NCH; ch++){
        #pragma unroll
        for (int tap=0; tap<9; tap++){
            const int kd = tap/3, kw = tap - kd*3;
            const int kc = tap*NCH + ch;
            const int tapoff = kd*ROWB + (kw*CIN + ch*32)*2;
            #pragma unroll
            for (int t=0;t<8;t++){
                int off = (tb[t] + tapoff) ^ swz[kw];
                short8 bv = *reinterpret_cast<const short8*>(lds + off);
                acc[0][t] = __builtin_amdgcn_mfma_f32_16x16x32_bf16(pa[kc][0], bv, acc[0][t], 0,0,0);
                acc[1][t] = __builtin_amdgcn_mfma_f32_16x16x32_bf16(pa[kc][1], bv, acc[1][t], 0,0,0);
            }
        }
    }

    // ---- epilogue ----
    #pragma unroll
    for (int c=0;c<2;c++){
        const int ct = h*2 + c;
        float s1[4] = {0.f,0.f,0.f,0.f};
        float s2[4] = {0.f,0.f,0.f,0.f};
        #pragma unroll
        for (int t=0;t<8;t++){
            float v[4];
            #pragma unroll
            for (int r=0;r<4;r++){
                float xv = acc[c][t][r]*mm[t];
                xv = (xv >= 0.f) ? xv : 0.01f*xv;
                v[r] = xv; s1[r] += xv; s2[r] += xv*xv;
            }
            unsigned lo = f2b(v[0]) | ((unsigned)f2b(v[1])<<16);
            unsigned hi = f2b(v[2]) | ((unsigned)f2b(v[3])<<16);
            *reinterpret_cast<uint2*>(outb + (size_t)ovox[t]*64 + ct*16 + g*4) = make_uint2(lo,hi);
        }
        #pragma unroll
        for (int r=0;r<4;r++){
            float a = s1[r], b = s2[r];
            a += __shfl_xor(a,1); b += __shfl_xor(b,1);
            a += __shfl_xor(a,2); b += __shfl_xor(b,2);
            a += __shfl_xor(a,4); b += __shfl_xor(b,4);
            a += __shfl_xor(a,8); b += __shfl_xor(b,8);
            if (lj == 0){
                atomicAdd(&sst[ct*16 + g*4 + r], a);
                atomicAdd(&sst[64 + ct*16 + g*4 + r], b);
            }
        }
    }
    __syncthreads();
    if (tid < 128){
        float* sg = statsN + (size_t)(blockIdx.x & (NSC-1))*128;
        atomicAdd(&sg[tid], sst[tid]);
    }
}

// ---------------- pool conv (round-6 known-good, untouched) ----------------
__launch_bounds__(256, 4)
__global__ void mpool(const unsigned short* __restrict__ in,   // bf16 [vox][64]
                      const unsigned short* __restrict__ Wt,   // bf16 [kc][64co][32k]
                      const float* __restrict__ mout,          // out_mask
                      float* __restrict__ outf)                // f32 [co][OSP]
{
    constexpr int ROWB = 34*64*2;
    __shared__ __align__(16) char lds[9*ROWB];

    const int tid = threadIdx.x;
    const int w = tid>>6, l = tid&63, g = l>>4, lj = l&15;

    int gi = (blockIdx.x & 7)*(gridDim.x>>3) + (blockIdx.x>>3);
    int z  = gi % OD1;
    int r0 = (gi / OD1)*4;

    const int sd3 = tid>>3;
    const int k0  = (tid&7)*8;

    int swz[3];
    #pragma unroll
    for (int kw=0;kw<3;kw++) swz[kw] = ((lj+kw)&7)<<4;
    const int woff = lj*32 + g*8;

    for (int i = tid; i < 9*2*8; i += 256){
        int rr = i / 16;
        int rem = i - rr*16;
        int slot = (rem >= 8) ? 33 : 0;
        int kc16 = rem & 7;
        int dst = rr*ROWB + slot*128 + kc16*16;
        dst ^= ((slot&7)<<4);
        *reinterpret_cast<uint4*>(lds + dst) = make_uint4(0,0,0,0);
    }

    int tb2[2], ovx[2];
    float om[2];
    #pragma unroll
    for (int t=0;t<2;t++){
        int o3 = t*16 + lj;
        tb2[t] = (o3*64 + g*8)*2;
        ovx[t] = (z*OD2 + (r0 + w))*OD3 + o3;
        om[t]  = mout[ovx[t]];
    }
    f32x4 acc[4][2];
    #pragma unroll
    for (int a=0;a<4;a++)
        #pragma unroll
        for (int b=0;b<2;b++)
            #pragma unroll
            for (int q=0;q<4;q++) acc[a][b][q] = 0.f;

    short8 pa[2][4], pb[2][2];
    const int rrb = 2*w;

    uint4 rv[9];
    auto issue_plane = [&](int kd, uint4 (&dst)[9]){
        int d1 = 2*z - 1 + kd;
        bool pok = ((unsigned)d1 < (unsigned)ND1);
        #pragma unroll
        for (int rr=0; rr<9; rr++){
            int d2 = 2*r0 - 1 + rr;
            dst[rr] = make_uint4(0,0,0,0);
            if (pok && ((unsigned)d2 < (unsigned)ND2)){
                int vox = (d1*ND2 + d2)*ND3 + sd3;
                dst[rr] = *reinterpret_cast<const uint4*>(in + (size_t)vox*64 + k0);
            }
        }
    };

    #pragma unroll 1
    for (int kd=0; kd<3; kd++){
        issue_plane(kd, rv);
        __syncthreads();
        #pragma unroll
        for (int rr=0; rr<9; rr++){
            int dst = (rr*ROWB + (((sd3+1)*64 + k0)*2)) ^ (((sd3+1)&7)<<4);
            *reinterpret_cast<uint4*>(lds + dst) = rv[rr];
        }
        __syncthreads();

        auto loadA2 = [&](int tap, int ch, int buf){
            const int kh = tap/3, kw = tap - kh*3;
            const int kc = ((kd*3+kh)*3+kw)*2 + ch;
            const unsigned short* wp = Wt + (size_t)kc*2048 + woff;
            #pragma unroll
            for (int ct=0;ct<4;ct++) pa[buf][ct] = *reinterpret_cast<const short8*>(wp + ct*512);
        };
        auto loadB2 = [&](int tap, int ch, int buf){
            const int kh = tap/3, kw = tap - kh*3;
            const int tapoff = (rrb + kh)*ROWB + (kw*64 + ch*32)*2;
            #pragma unroll
            for (int t=0;t<2;t++){
                int off = (tb2[t] + tapoff) ^ swz[kw];
                pb[buf][t] = *reinterpret_cast<const short8*>(lds + off);
            }
        };

        #pragma unroll 1
        for (int ch=0; ch<2; ch++){
            loadA2(0, ch, 0); loadB2(0, ch, 0);
            #pragma unroll
            for (int tap=0; tap<9; tap++){
                const int cb = tap&1, nb = (tap&1)^1;
                if (tap < 8){ loadA2(tap+1, ch, nb); loadB2(tap+1, ch, nb); }
                #pragma unroll
                for (int t=0;t<2;t++)
                    #pragma unroll
                    for (int ct=0; ct<4; ct++)
                        acc[ct][t] = __builtin_amdgcn_mfma_f32_16x16x32_bf16(pa[cb][ct], pb[cb][t], acc[ct][t], 0,0,0);
            }
        }
    }
    #pragma unroll
    for (int t=0;t<2;t++){
        #pragma unroll
        for (int ct=0;ct<4;ct++){
            #pragma unroll
            for (int r=0;r<4;r++){
                int co = ct*16 + g*4 + r;
                outf[(size_t)co*OSP + ovx[t]] = acc[ct][t][r]*om[t];
            }
        }
    }
}

// ---------------- launch ----------------
extern "C" void kernel_launch(void* const* d_in, const int* in_sizes, int n_in,
                              void* d_out, int out_size, void* d_ws, size_t ws_size,
                              hipStream_t stream)
{
    const float* x      = (const float*)d_in[0];
    const void*  mraw   = d_in[1];
    const float* W_A1   = (const float*)d_in[2];
    const float* W_A2   = (const float*)d_in[3];
    const float* W_B1   = (const float*)d_in[4];
    const float* W_B2   = (const float*)d_in[5];
    const float* W_pool = (const float*)d_in[6];
    const float* g_A1 = (const float*)d_in[7],  *b_A1 = (const float*)d_in[8];
    const float* g_A2 = (const float*)d_in[9],  *b_A2 = (const float*)d_in[10];
    const float* g_B1 = (const float*)d_in[11], *b_B1 = (const float*)d_in[12];
    const float* g_B2 = (const float*)d_in[13], *b_B2 = (const float*)d_in[14];

    char* p = (char*)d_ws;
    float* m     = (float*)p; p += (size_t)SP*4;
    float* omask = (float*)p; p += (size_t)OSP*4;
    float* statsN= (float*)p; p += 4*NSC*128*4;
    float* scsh  = (float*)p; p += 4*128*4;
    float* nactN = (float*)p; p += NSC*4;
    int*   flag  = (int*)p;   p += 4;
    p += 252;
    unsigned short* WtA1 = (unsigned short*)p; p += 288*64*2;
    unsigned short* WtA2 = (unsigned short*)p; p += 576*64*2;
    unsigned short* WtB1 = (unsigned short*)p; p += 288*64*2;
    unsigned short* WtB2 = (unsigned short*)p; p += 576*64*2;
    unsigned short* WtP  = (unsigned short*)p; p += 1728*64*2;
    unsigned short* X = (unsigned short*)p; p += (size_t)SP*32*2;
    unsigned short* P = (unsigned short*)p; p += (size_t)SP*64*2;
    unsigned short* Q = (unsigned short*)p; p += (size_t)SP*64*2;
    unsigned short* R = (unsigned short*)p; p += (size_t)SP*64*2;

    float* down = (float*)d_out;                 // [64][OSP]
    float* resf = down + (size_t)CO*OSP;         // [64][SP]

    hipMemsetAsync(statsN, 0, (4*NSC*128 + 4*128 + NSC)*4 + 4, stream);
    k_detect<<<256, 256, 0, stream>>>((const unsigned char*)mraw, flag);
    k_mask<<<SP/256, 256, 0, stream>>>(mraw, flag, m, nactN);
    k_outmask<<<OSP/256, 256, 0, stream>>>(m, omask);
    k_prep_x<<<SP/64, 256, 0, stream>>>(x, m, X);

    k_wprep<<<(64*288+255)/256, 256, 0, stream>>>(W_A1, WtA1, 32, 9);
    k_wprep<<<(64*576+255)/256, 256, 0, stream>>>(W_A2, WtA2, 64, 9);
    k_wprep<<<(64*288+255)/256, 256, 0, stream>>>(W_B1, WtB1, 32, 9);
    k_wprep<<<(64*576+255)/256, 256, 0, stream>>>(W_B2, WtB2, 64, 9);
    k_wprep<<<(64*1728+255)/256, 256, 0, stream>>>(W_pool, WtP, 64, 27);

    float* SA1 = statsN + 0*NSC*128;
    float* SA2 = statsN + 1*NSC*128;
    float* SB1 = statsN + 2*NSC*128;
    float* SB2 = statsN + 3*NSC*128;

    // stage 1: A1 and B1 (both read X)
    mconv10<0,32,false><<<3200, 256, 0, stream>>>(X, WtA1, nullptr, nullptr, m, P, SA1);
    mconv10<1,32,false><<<3200, 256, 0, stream>>>(X, WtB1, nullptr, nullptr, m, Q, SB1);
    k_finalize2<<<2, 64, 0, stream>>>(SA1, g_A1, b_A1, scsh + 0,
                                      SB1, g_B1, b_B1, scsh + 256, nactN);
    // stage 2: A2 on BN_A1(P), B2 on BN_B1(Q) (affine fused in staging)
    mconv10<1,64,true><<<3200, 256, 0, stream>>>(P, WtA2, scsh + 0,   m, m, R, SA2);
    mconv10<0,64,true><<<3200, 256, 0, stream>>>(Q, WtB2, scsh + 256, m, m, P, SB2);
    k_finalize2<<<2, 64, 0, stream>>>(SA2, g_A2, b_A2, scsh + 128,
                                      SB2, g_B2, b_B2, scsh + 384, nactN);
    // res_B combine -> Q (bf16 for pool) + resf (f32 output)
    k_resB<<<SP/64, 256, 0, stream>>>(R, P, scsh + 128, scsh + 384, m, Q, resf);
    // pool
    mpool<<<1600, 256, 0, stream>>>(Q, WtP, omask, down);
}